// Round 2
// baseline (366.924 us; speedup 1.0000x reference)
//
#include <hip/hip_runtime.h>
#include <hip/hip_bf16.h>

#define BATCH 4
#define SEQ 4096
#define DMODEL 2048
#define HD 128
#define BS (BATCH*SEQ)

typedef __attribute__((ext_vector_type(8))) short short8;
typedef __attribute__((ext_vector_type(4))) float f32x4;
typedef __attribute__((ext_vector_type(4))) float float4v;
typedef unsigned short u16;
typedef unsigned int u32;

#define LOG2E 1.4426950408889634f
#define SCALE 0.08838834764831845f /* 1/sqrt(128) */

__device__ __forceinline__ u16 f2bf(float f){
  u32 u = __builtin_bit_cast(u32, f);
  u32 r = (u + 0x7FFFu + ((u >> 16) & 1u)) >> 16;
  return (u16)r;
}

__device__ __forceinline__ void gload16(const void* gptr, void* lptr){
  __builtin_amdgcn_global_load_lds((const __attribute__((address_space(1))) void*)gptr,
                                   (__attribute__((address_space(3))) void*)lptr, 16, 0, 0);
}

// ---------------- trig table: tab[s*64+j] = (cos, sin)(s * 10000^(-j/64)) ----------------
__global__ __launch_bounds__(256) void k_tab(float2* __restrict__ tab){
  int i = blockIdx.x*256 + threadIdx.x;      // 4096*64 total
  int s = i >> 6, j = i & 63;
  float invf = (float)pow(10000.0, -(double)j/64.0);
  float ang  = (float)s * invf;              // mimic fp32 reference rounding of the angle
  double a = (double)ang;
  tab[i] = make_float2((float)cos(a), (float)sin(a));
}

// ---------------- x fp32 -> bf16 ----------------
__global__ __launch_bounds__(256) void k_cvtx(const float* __restrict__ x, u16* __restrict__ xb){
  size_t i = (size_t)blockIdx.x*256 + threadIdx.x;   // each handles 8 elems; grid exact
  const float4v* xp = (const float4v*)x;
  float4v a = xp[i*2], c = xp[i*2+1];
  short8 o;
  o[0]=(short)f2bf(a[0]); o[1]=(short)f2bf(a[1]); o[2]=(short)f2bf(a[2]); o[3]=(short)f2bf(a[3]);
  o[4]=(short)f2bf(c[0]); o[5]=(short)f2bf(c[1]); o[6]=(short)f2bf(c[2]); o[7]=(short)f2bf(c[3]);
  *(short8*)(xb + i*8) = o;
}

// ---------------- weights fp32 -> bf16 (wq|wk|wv packed) ----------------
__global__ __launch_bounds__(256) void k_cvtw(const float* __restrict__ wq, const float* __restrict__ wk,
                                              const float* __restrict__ wv, u16* __restrict__ wb){
  int i = blockIdx.x*256 + threadIdx.x;      // 3*262144 total
  int m = i >> 18; int r = i & 262143;
  const float* s = (m==0) ? wq : ((m==1) ? wk : wv);
  wb[i] = f2bf(s[r]);
}

// ---------------- QKV projection GEMM + fused RoPE / V-transpose epilogue ----------------
// grid (128, 3): x-tile of 128 rows; y selects q/k/v. 4 waves, each 32 rows x 128 cols.
__global__ __launch_bounds__(256) void k_gemm(
    const u16* __restrict__ xb, const u16* __restrict__ wb, const float2* __restrict__ tab,
    u16* __restrict__ qb, u16* __restrict__ kb, u16* __restrict__ vt)
{
  __shared__ u16 lA[128*64];   // swizzled rows: byte = row*128 + (cb ^ ((row&7)<<4))
  __shared__ u16 lW[128*64];
  const int tid = threadIdx.x;
  const int wsel = blockIdx.y;
  const size_t M0 = (size_t)blockIdx.x * 128;
  const u16* Wm = wb + (size_t)wsel * (HD*DMODEL);
  const int w = tid >> 6, lane = tid & 63, lr = lane & 15, lg = lane >> 4;

  f32x4 acc[2][8];
  #pragma unroll
  for (int i=0;i<2;i++)
    #pragma unroll
    for (int j=0;j<8;j++) acc[i][j] = f32x4{0.f,0.f,0.f,0.f};

  const int Lb = tid*16;
  int srow[4], soff[4];
  #pragma unroll
  for (int i=0;i<4;i++){
    int L = i*4096 + Lb;
    int row = L >> 7, cb = L & 127;
    int scb = cb ^ ((row & 7) << 4);
    srow[i] = row; soff[i] = scb >> 1;
  }

  for (int k0 = 0; k0 < DMODEL; k0 += 64){
    #pragma unroll
    for (int i=0;i<4;i++){
      gload16(xb + (M0 + srow[i])*DMODEL + k0 + soff[i], ((char*)lA) + i*4096 + Lb);
      gload16(Wm + (size_t)srow[i]*DMODEL + k0 + soff[i], ((char*)lW) + i*4096 + Lb);
    }
    __syncthreads();
    short8 afr[2][2], bfr[8][2];
    #pragma unroll
    for (int rf=0; rf<2; rf++)
      #pragma unroll
      for (int ks=0; ks<2; ks++){
        int r = w*32 + rf*16 + lr;
        int byte = r*128 + ((ks*64 + lg*16) ^ ((r&7)<<4));
        afr[rf][ks] = *(const short8*)((const char*)lA + byte);
      }
    #pragma unroll
    for (int nf=0; nf<8; nf++)
      #pragma unroll
      for (int ks=0; ks<2; ks++){
        int r = nf*16 + lr;
        int byte = r*128 + ((ks*64 + lg*16) ^ ((r&7)<<4));
        bfr[nf][ks] = *(const short8*)((const char*)lW + byte);
      }
    #pragma unroll
    for (int rf=0; rf<2; rf++)
      #pragma unroll
      for (int nf=0; nf<8; nf++){
        acc[rf][nf] = __builtin_amdgcn_mfma_f32_16x16x32_bf16(afr[rf][0], bfr[nf][0], acc[rf][nf], 0,0,0);
        acc[rf][nf] = __builtin_amdgcn_mfma_f32_16x16x32_bf16(afr[rf][1], bfr[nf][1], acc[rf][nf], 0,0,0);
      }
    __syncthreads();
  }

  if (wsel < 2){
    u16* dst = (wsel == 0) ? qb : kb;
    #pragma unroll
    for (int rf=0; rf<2; rf++){
      #pragma unroll
      for (int reg=0; reg<4; reg++){
        size_t grow = M0 + w*32 + rf*16 + lg*4 + reg;
        int spos = (int)(grow & (SEQ-1));
        #pragma unroll
        for (int cf=0; cf<4; cf++){
          int j = cf*16 + lr;                 // 0..63
          float2 cs = tab[spos*64 + j];
          float lo = acc[rf][cf][reg];
          float hi = acc[rf][cf+4][reg];
          dst[grow*HD + j]      = f2bf(lo*cs.x - hi*cs.y);
          dst[grow*HD + j + 64] = f2bf(hi*cs.x + lo*cs.y);
        }
      }
    }
  } else {
    #pragma unroll
    for (int rf=0; rf<2; rf++)
      #pragma unroll
      for (int reg=0; reg<4; reg++){
        size_t grow = M0 + w*32 + rf*16 + lg*4 + reg;
        size_t b = grow >> 12;
        size_t spos = grow & (SEQ-1);
        #pragma unroll
        for (int cf=0; cf<8; cf++){
          int col = cf*16 + lr;
          vt[(b*HD + col)*SEQ + spos] = f2bf(acc[rf][cf][reg]);
        }
      }
  }
}

// ---------------- causal flash attention: 1 wave per 16-row q-tile ----------------
// grid 1024, block 64. No inter-wave sync; K and V^T fragments read directly from
// global (L2-resident: 2 MB per batch). Per-wave swizzled lP for P redistribution.
// XCD mapping: bid%8 = XCD (round-robin heuristic); 2 XCDs per batch; qt strided
// by 2 within an XCD and descending so heavy tiles dispatch first.
__global__ __launch_bounds__(64,4) void k_attn(
    const u16* __restrict__ qb, const u16* __restrict__ kb, const u16* __restrict__ vt,
    float* __restrict__ out)
{
  __shared__ u16 lP[16*64];     // byte = r*128 + (cb ^ ((r&7)<<4))
  const int lane = threadIdx.x & 63, lr = lane & 15, lg = lane >> 4;
  const int bid = blockIdx.x;
  const int x = bid & 7, idx = bid >> 3;
  const int b = x >> 1;
  const int qt = 255 - (idx*2 + (x & 1));      // 0..255
  const int nkt = (qt + 4) >> 2;               // ceil((qt+1)*16 / 64)

  const u16* Kb = kb + (size_t)b*SEQ*HD;
  const u16* Vb = vt + (size_t)b*HD*SEQ;

  short8 aq[4];
  const u16* qp = qb + ((size_t)b*SEQ + qt*16 + lr)*HD + lg*8;
  #pragma unroll
  for (int ks=0; ks<4; ks++) aq[ks] = *(const short8*)(qp + ks*32);

  f32x4 accO[8];
  #pragma unroll
  for (int i=0;i<8;i++) accO[i] = f32x4{0.f,0.f,0.f,0.f};
  float m2[4]   = {-1e30f,-1e30f,-1e30f,-1e30f};
  float lsum[4] = {0.f,0.f,0.f,0.f};
  const float cfac = SCALE * LOG2E;

  for (int kt = 0; kt < nkt; kt++){
    const int kv0 = kt*64;
    // ---- S = Q K^T (16 q x 64 kv), log2 domain ----
    f32x4 sc[4];
    #pragma unroll
    for (int nf=0; nf<4; nf++){
      sc[nf] = f32x4{0.f,0.f,0.f,0.f};
      const u16* kp = Kb + (size_t)(kv0 + nf*16 + lr)*HD + lg*8;
      #pragma unroll
      for (int ks=0; ks<4; ks++){
        short8 bk = *(const short8*)(kp + ks*32);
        sc[nf] = __builtin_amdgcn_mfma_f32_16x16x32_bf16(aq[ks], bk, sc[nf], 0,0,0);
      }
      sc[nf] *= cfac;
    }
    if (kt == nkt-1){
      #pragma unroll
      for (int nf=0; nf<4; nf++)
        #pragma unroll
        for (int reg=0; reg<4; reg++){
          int kv = kv0 + nf*16 + lr;
          int q  = qt*16 + lg*4 + reg;
          if (kv > q) sc[nf][reg] = -1e30f;
        }
    }
    // ---- online softmax (per q-row = (lg,reg); kv spread over lr and nf) ----
    float al[4];
    #pragma unroll
    for (int reg=0; reg<4; reg++){
      float v = fmaxf(fmaxf(sc[0][reg], sc[1][reg]), fmaxf(sc[2][reg], sc[3][reg]));
      v = fmaxf(v, __shfl_xor(v, 1));
      v = fmaxf(v, __shfl_xor(v, 2));
      v = fmaxf(v, __shfl_xor(v, 4));
      v = fmaxf(v, __shfl_xor(v, 8));
      float mnew = fmaxf(m2[reg], v);
      al[reg] = exp2f(m2[reg] - mnew);
      m2[reg] = mnew;
    }
    float prs[4] = {0.f,0.f,0.f,0.f};
    #pragma unroll
    for (int nf=0; nf<4; nf++)
      #pragma unroll
      for (int reg=0; reg<4; reg++){
        float p = exp2f(sc[nf][reg] - m2[reg]);
        prs[reg] += p;
        int r = lg*4 + reg;
        int byte = r*128 + ((nf*32 + lr*2) ^ ((r&7)<<4));
        *(u16*)(((char*)lP) + byte) = f2bf(p);
      }
    f32x4 alv = f32x4{al[0], al[1], al[2], al[3]};
    #pragma unroll
    for (int reg=0; reg<4; reg++){
      float v = prs[reg];
      v += __shfl_xor(v, 1);
      v += __shfl_xor(v, 2);
      v += __shfl_xor(v, 4);
      v += __shfl_xor(v, 8);
      lsum[reg] = lsum[reg]*al[reg] + v;
    }
    #pragma unroll
    for (int cf=0; cf<8; cf++) accO[cf] *= alv;

    // ---- O += P V (P from per-wave LDS; V^T fragments direct from global) ----
    short8 pa[2];
    #pragma unroll
    for (int ks=0; ks<2; ks++){
      int byte = lr*128 + ((ks*64 + lg*16) ^ ((lr&7)<<4));
      pa[ks] = *(const short8*)(((const char*)lP) + byte);
    }
    #pragma unroll
    for (int cf=0; cf<8; cf++){
      const u16* vp = Vb + (size_t)(cf*16 + lr)*SEQ + kv0 + lg*8;
      #pragma unroll
      for (int ks=0; ks<2; ks++){
        short8 bv = *(const short8*)(vp + ks*32);
        accO[cf] = __builtin_amdgcn_mfma_f32_16x16x32_bf16(pa[ks], bv, accO[cf], 0,0,0);
      }
    }
  }

  #pragma unroll
  for (int reg=0; reg<4; reg++){
    float inv = 1.0f / lsum[reg];
    size_t orow = (size_t)b*SEQ + qt*16 + lg*4 + reg;
    #pragma unroll
    for (int cf=0; cf<8; cf++)
      out[orow*HD + cf*16 + lr] = accO[cf][reg] * inv;
  }
}

extern "C" void kernel_launch(void* const* d_in, const int* in_sizes, int n_in,
                              void* d_out, int out_size, void* d_ws, size_t ws_size,
                              hipStream_t stream){
  const float* x  = (const float*)d_in[0];
  const float* wq = (const float*)d_in[1];
  const float* wk = (const float*)d_in[2];
  const float* wv = (const float*)d_in[3];
  float* out = (float*)d_out;
  char* ws = (char*)d_ws;

  size_t off = 0;
  u16* xb = (u16*)(ws + off); off += (size_t)BS*DMODEL*2;     // 64 MB
  u16* wb = (u16*)(ws + off); off += (size_t)3*HD*DMODEL*2;   // 1.5 MB
  float2* tab = (float2*)(ws + off); off += (size_t)SEQ*64*8; // 2 MB
  u16* qb = (u16*)(ws + off); off += (size_t)BS*HD*2;         // 4 MB
  u16* kb = (u16*)(ws + off); off += (size_t)BS*HD*2;         // 4 MB
  u16* vt = (u16*)(ws + off); off += (size_t)BS*HD*2;         // 4 MB
  if (ws_size < off) return;  // insufficient workspace -> fail visibly

  hipLaunchKernelGGL(k_tab,  dim3(1024),  dim3(256), 0, stream, tab);
  hipLaunchKernelGGL(k_cvtx, dim3(16384), dim3(256), 0, stream, x, xb);
  hipLaunchKernelGGL(k_cvtw, dim3(3072),  dim3(256), 0, stream, wq, wk, wv, wb);
  hipLaunchKernelGGL(k_gemm, dim3(128,3), dim3(256), 0, stream, xb, wb, tab, qb, kb, vt);
  hipLaunchKernelGGL(k_attn, dim3(1024),  dim3(64),  0, stream, qb, kb, vt, out);
}

// Round 3
// 138.440 us; speedup vs baseline: 2.6504x; 2.6504x over previous
//
#include <hip/hip_runtime.h>
#include <hip/hip_bf16.h>

#define BATCH 4
#define SEQ 4096
#define DMODEL 2048
#define HD 128
#define BS (BATCH*SEQ)

typedef __attribute__((ext_vector_type(8))) short short8;
typedef __attribute__((ext_vector_type(4))) float f32x4;
typedef __attribute__((ext_vector_type(4))) float float4v;
typedef unsigned short u16;
typedef unsigned int u32;

#define LOG2E 1.4426950408889634f
#define SCALE 0.08838834764831845f /* 1/sqrt(128) */

__device__ __forceinline__ u16 f2bf(float f){
  u32 u = __builtin_bit_cast(u32, f);
  u32 r = (u + 0x7FFFu + ((u >> 16) & 1u)) >> 16;
  return (u16)r;
}

__device__ __forceinline__ void gload16(const void* gptr, void* lptr){
  __builtin_amdgcn_global_load_lds((const __attribute__((address_space(1))) void*)gptr,
                                   (__attribute__((address_space(3))) void*)lptr, 16, 0, 0);
}

// ---------------- trig table: tab[s*64+j] = (cos, sin)(s * 10000^(-j/64)) ----------------
__global__ __launch_bounds__(256) void k_tab(float2* __restrict__ tab){
  int i = blockIdx.x*256 + threadIdx.x;      // 4096*64 total
  int s = i >> 6, j = i & 63;
  float invf = (float)pow(10000.0, -(double)j/64.0);
  float ang  = (float)s * invf;              // mimic fp32 reference rounding of the angle
  double a = (double)ang;
  tab[i] = make_float2((float)cos(a), (float)sin(a));
}

// ---------------- x fp32 -> bf16 ----------------
__global__ __launch_bounds__(256) void k_cvtx(const float* __restrict__ x, u16* __restrict__ xb){
  size_t i = (size_t)blockIdx.x*256 + threadIdx.x;   // each handles 8 elems; grid exact
  const float4v* xp = (const float4v*)x;
  float4v a = xp[i*2], c = xp[i*2+1];
  short8 o;
  o[0]=(short)f2bf(a[0]); o[1]=(short)f2bf(a[1]); o[2]=(short)f2bf(a[2]); o[3]=(short)f2bf(a[3]);
  o[4]=(short)f2bf(c[0]); o[5]=(short)f2bf(c[1]); o[6]=(short)f2bf(c[2]); o[7]=(short)f2bf(c[3]);
  *(short8*)(xb + i*8) = o;
}

// ---------------- weights fp32 -> bf16 (wq|wk|wv packed) ----------------
__global__ __launch_bounds__(256) void k_cvtw(const float* __restrict__ wq, const float* __restrict__ wk,
                                              const float* __restrict__ wv, u16* __restrict__ wb){
  int i = blockIdx.x*256 + threadIdx.x;      // 3*262144 total
  int m = i >> 18; int r = i & 262143;
  const float* s = (m==0) ? wq : ((m==1) ? wk : wv);
  wb[i] = f2bf(s[r]);
}

// ---------------- QKV projection GEMM + fused RoPE / V-transpose epilogue ----------------
// grid (128, 3): x-tile of 128 rows; y selects q/k/v. 4 waves, each 32 rows x 128 cols.
__global__ __launch_bounds__(256) void k_gemm(
    const u16* __restrict__ xb, const u16* __restrict__ wb, const float2* __restrict__ tab,
    u16* __restrict__ qb, u16* __restrict__ kb, u16* __restrict__ vt)
{
  __shared__ u16 lA[128*64];   // swizzled rows: byte = row*128 + (cb ^ ((row&7)<<4))
  __shared__ u16 lW[128*64];
  const int tid = threadIdx.x;
  const int wsel = blockIdx.y;
  const size_t M0 = (size_t)blockIdx.x * 128;
  const u16* Wm = wb + (size_t)wsel * (HD*DMODEL);
  const int w = tid >> 6, lane = tid & 63, lr = lane & 15, lg = lane >> 4;

  f32x4 acc[2][8];
  #pragma unroll
  for (int i=0;i<2;i++)
    #pragma unroll
    for (int j=0;j<8;j++) acc[i][j] = f32x4{0.f,0.f,0.f,0.f};

  const int Lb = tid*16;
  int srow[4], soff[4];
  #pragma unroll
  for (int i=0;i<4;i++){
    int L = i*4096 + Lb;
    int row = L >> 7, cb = L & 127;
    int scb = cb ^ ((row & 7) << 4);
    srow[i] = row; soff[i] = scb >> 1;
  }

  for (int k0 = 0; k0 < DMODEL; k0 += 64){
    #pragma unroll
    for (int i=0;i<4;i++){
      gload16(xb + (M0 + srow[i])*DMODEL + k0 + soff[i], ((char*)lA) + i*4096 + Lb);
      gload16(Wm + (size_t)srow[i]*DMODEL + k0 + soff[i], ((char*)lW) + i*4096 + Lb);
    }
    __syncthreads();
    short8 afr[2][2], bfr[8][2];
    #pragma unroll
    for (int rf=0; rf<2; rf++)
      #pragma unroll
      for (int ks=0; ks<2; ks++){
        int r = w*32 + rf*16 + lr;
        int byte = r*128 + ((ks*64 + lg*16) ^ ((r&7)<<4));
        afr[rf][ks] = *(const short8*)((const char*)lA + byte);
      }
    #pragma unroll
    for (int nf=0; nf<8; nf++)
      #pragma unroll
      for (int ks=0; ks<2; ks++){
        int r = nf*16 + lr;
        int byte = r*128 + ((ks*64 + lg*16) ^ ((r&7)<<4));
        bfr[nf][ks] = *(const short8*)((const char*)lW + byte);
      }
    #pragma unroll
    for (int rf=0; rf<2; rf++)
      #pragma unroll
      for (int nf=0; nf<8; nf++){
        acc[rf][nf] = __builtin_amdgcn_mfma_f32_16x16x32_bf16(afr[rf][0], bfr[nf][0], acc[rf][nf], 0,0,0);
        acc[rf][nf] = __builtin_amdgcn_mfma_f32_16x16x32_bf16(afr[rf][1], bfr[nf][1], acc[rf][nf], 0,0,0);
      }
    __syncthreads();
  }

  if (wsel < 2){
    u16* dst = (wsel == 0) ? qb : kb;
    #pragma unroll
    for (int rf=0; rf<2; rf++){
      #pragma unroll
      for (int reg=0; reg<4; reg++){
        size_t grow = M0 + w*32 + rf*16 + lg*4 + reg;
        int spos = (int)(grow & (SEQ-1));
        #pragma unroll
        for (int cf=0; cf<4; cf++){
          int j = cf*16 + lr;                 // 0..63
          float2 cs = tab[spos*64 + j];
          float lo = acc[rf][cf][reg];
          float hi = acc[rf][cf+4][reg];
          dst[grow*HD + j]      = f2bf(lo*cs.x - hi*cs.y);
          dst[grow*HD + j + 64] = f2bf(hi*cs.x + lo*cs.y);
        }
      }
    }
  } else {
    #pragma unroll
    for (int rf=0; rf<2; rf++)
      #pragma unroll
      for (int reg=0; reg<4; reg++){
        size_t grow = M0 + w*32 + rf*16 + lg*4 + reg;
        size_t b = grow >> 12;
        size_t spos = grow & (SEQ-1);
        #pragma unroll
        for (int cf=0; cf<8; cf++){
          int col = cf*16 + lr;
          vt[(b*HD + col)*SEQ + spos] = f2bf(acc[rf][cf][reg]);
        }
      }
  }
}

// ---------------- causal flash attention, 4-way KV split (flash-decoding) ----------------
// grid 1024: (batch, 64-row q-tile, kv-split). 4 waves x 16 q-rows share staged lK/lV.
// Each block computes online softmax over its contiguous KV chunk, writes partial
// (O, m, l). LDS 40KB -> 4 blocks/CU -> 16 waves/CU. qt descending (heavy first);
// bid&7 -> XCD pairs per batch so each XCD's L2 holds one batch's K+V (2MB).
__global__ __launch_bounds__(256) void k_attn(
    const u16* __restrict__ qbuf, const u16* __restrict__ kb, const u16* __restrict__ vt,
    float* __restrict__ Opart, float2* __restrict__ ml)
{
  __shared__ u16 lK[64*128];    // byte = kv*256 + (cb ^ ((kv&7)<<4))
  __shared__ u16 lV[128*64];    // byte = d*128  + (cb ^ ((d&7)<<4))
  __shared__ u16 lP[4][16*64];  // per-wave, byte = r*128 + (cb ^ ((r&7)<<4))
  const int tid = threadIdx.x;
  const int bid = blockIdx.x;
  const int x = bid & 7, idx = bid >> 3;
  const int b = x >> 1, half = x & 1;
  const int qt = 63 - (idx >> 1);              // heavy tiles first
  const int sp = (idx & 1) + 2*half;           // kv-split 0..3
  const int qbn = b*64 + qt;                   // 0..255
  const int w = tid >> 6, lane = tid & 63, lr = lane & 15, lg = lane >> 4;

  // balanced contiguous partition of tiles [0, qt] into 4 chunks
  const int n = qt + 1, cbase = n >> 2, crem = n & 3;
  const int cnt = cbase + (sp < crem ? 1 : 0);
  const int klo = sp*cbase + (sp < crem ? sp : crem);
  const int khi = klo + cnt;
  const size_t prow0 = ((size_t)qbn*4 + sp)*64;

  if (cnt == 0){                               // empty split: mark and exit (block-uniform)
    if (lr == 0){
      #pragma unroll
      for (int reg=0; reg<4; reg++)
        ml[prow0 + w*16 + lg*4 + reg] = make_float2(-1e30f, 0.f);
    }
    return;
  }

  const size_t qrow = (size_t)b*SEQ + qt*64 + w*16 + lr;
  short8 aq[4];
  #pragma unroll
  for (int ks=0; ks<4; ks++)
    aq[ks] = *(const short8*)(qbuf + qrow*HD + ks*32 + lg*8);

  f32x4 accO[8];
  #pragma unroll
  for (int i=0;i<8;i++) accO[i] = f32x4{0.f,0.f,0.f,0.f};
  float m2[4]   = {-1e30f,-1e30f,-1e30f,-1e30f};
  float lsum[4] = {0.f,0.f,0.f,0.f};

  const int Lb = tid*16;
  const float cfac = SCALE * LOG2E;

  for (int kt = klo; kt < khi; kt++){
    #pragma unroll
    for (int i=0;i<4;i++){
      int L = i*4096 + Lb;
      { int row = L >> 8, cb = L & 255;
        int scb = cb ^ ((row & 7) << 4);
        gload16(kb + ((size_t)b*SEQ + kt*64 + row)*HD + (scb>>1), ((char*)lK) + L); }
      { int row = L >> 7, cb = L & 127;
        int scb = cb ^ ((row & 7) << 4);
        gload16(vt + ((size_t)b*HD + row)*SEQ + kt*64 + (scb>>1), ((char*)lV) + L); }
    }
    __syncthreads();

    // S = Q K^T  (16 q-rows x 64 kv) in log2-domain units
    f32x4 sc[4];
    #pragma unroll
    for (int nf=0; nf<4; nf++){
      sc[nf] = f32x4{0.f,0.f,0.f,0.f};
      #pragma unroll
      for (int ks=0; ks<4; ks++){
        int r = nf*16 + lr;
        int byte = r*256 + ((ks*64 + lg*16) ^ ((r&7)<<4));
        short8 bk = *(const short8*)((const char*)lK + byte);
        sc[nf] = __builtin_amdgcn_mfma_f32_16x16x32_bf16(aq[ks], bk, sc[nf], 0,0,0);
      }
      sc[nf] *= cfac;
    }
    if (kt == qt){                            // diagonal tile: causal mask
      #pragma unroll
      for (int nf=0; nf<4; nf++)
        #pragma unroll
        for (int reg=0; reg<4; reg++){
          int col = nf*16 + lr;
          int row = w*16 + lg*4 + reg;
          if (col > row) sc[nf][reg] = -1e30f;
        }
    }
    float al[4];
    #pragma unroll
    for (int reg=0; reg<4; reg++){
      float v = fmaxf(fmaxf(sc[0][reg], sc[1][reg]), fmaxf(sc[2][reg], sc[3][reg]));
      v = fmaxf(v, __shfl_xor(v, 1));
      v = fmaxf(v, __shfl_xor(v, 2));
      v = fmaxf(v, __shfl_xor(v, 4));
      v = fmaxf(v, __shfl_xor(v, 8));
      float mnew = fmaxf(m2[reg], v);
      al[reg] = exp2f(m2[reg] - mnew);
      m2[reg] = mnew;
    }
    float prs[4] = {0.f,0.f,0.f,0.f};
    #pragma unroll
    for (int nf=0; nf<4; nf++)
      #pragma unroll
      for (int reg=0; reg<4; reg++){
        float p = exp2f(sc[nf][reg] - m2[reg]);
        prs[reg] += p;
        int r = lg*4 + reg;
        int byte = r*128 + ((nf*32 + lr*2) ^ ((r&7)<<4));
        *(u16*)(((char*)lP[w]) + byte) = f2bf(p);
      }
    f32x4 alv = f32x4{al[0], al[1], al[2], al[3]};
    #pragma unroll
    for (int reg=0; reg<4; reg++){
      float v = prs[reg];
      v += __shfl_xor(v, 1);
      v += __shfl_xor(v, 2);
      v += __shfl_xor(v, 4);
      v += __shfl_xor(v, 8);
      lsum[reg] = lsum[reg]*al[reg] + v;
    }
    #pragma unroll
    for (int cf=0; cf<8; cf++) accO[cf] *= alv;

    short8 pa[2];
    #pragma unroll
    for (int ks=0; ks<2; ks++){
      int byte = lr*128 + ((ks*64 + lg*16) ^ ((lr&7)<<4));
      pa[ks] = *(const short8*)(((const char*)lP[w]) + byte);
    }
    #pragma unroll
    for (int cf=0; cf<8; cf++){
      #pragma unroll
      for (int ks=0; ks<2; ks++){
        int d = cf*16 + lr;
        int byte = d*128 + ((ks*64 + lg*16) ^ ((d&7)<<4));
        short8 bv = *(const short8*)(((const char*)lV) + byte);
        accO[cf] = __builtin_amdgcn_mfma_f32_16x16x32_bf16(pa[ks], bv, accO[cf], 0,0,0);
      }
    }
    __syncthreads();
  }

  // partial epilogue: raw accO + (m, l) per row
  #pragma unroll
  for (int reg=0; reg<4; reg++){
    size_t pr = prow0 + w*16 + lg*4 + reg;
    #pragma unroll
    for (int cf=0; cf<8; cf++)
      Opart[pr*HD + cf*16 + lr] = accO[cf][reg];
  }
  if (lr == 0){
    #pragma unroll
    for (int reg=0; reg<4; reg++)
      ml[prow0 + w*16 + lg*4 + reg] = make_float2(m2[reg], lsum[reg]);
  }
}

// ---------------- combine partials: out = sum_s O_s * 2^(m_s-M) / L ----------------
__global__ __launch_bounds__(256) void k_comb(
    const float* __restrict__ Opart, const float2* __restrict__ ml, float* __restrict__ out)
{
  const int t = threadIdx.x;
  const int r = blockIdx.x*8 + (t >> 5);       // global row 0..16383
  const int c = (t & 31)*4;
  const int qbn = r >> 6, rr = r & 63;
  float m[4], l[4], M = -1e30f;
  #pragma unroll
  for (int s=0; s<4; s++){
    float2 v = ml[((size_t)qbn*4 + s)*64 + rr];
    m[s] = v.x; l[s] = v.y;
    M = fmaxf(M, m[s]);
  }
  float L = 0.f;
  #pragma unroll
  for (int s=0; s<4; s++){ m[s] = exp2f(m[s] - M); L += l[s]*m[s]; }
  const float inv = 1.0f / L;
  f32x4 acc = f32x4{0.f,0.f,0.f,0.f};
  #pragma unroll
  for (int s=0; s<4; s++){
    f32x4 o = *(const f32x4*)(Opart + (((size_t)qbn*4 + s)*64 + rr)*(size_t)HD + c);
    float sc = m[s]*inv;
    acc += o * sc;
  }
  *(f32x4*)(out + (size_t)r*HD + c) = acc;
}

extern "C" void kernel_launch(void* const* d_in, const int* in_sizes, int n_in,
                              void* d_out, int out_size, void* d_ws, size_t ws_size,
                              hipStream_t stream){
  const float* x  = (const float*)d_in[0];
  const float* wq = (const float*)d_in[1];
  const float* wk = (const float*)d_in[2];
  const float* wv = (const float*)d_in[3];
  float* out = (float*)d_out;
  char* ws = (char*)d_ws;

  size_t off = 0;
  u16* xb = (u16*)(ws + off); off += (size_t)BS*DMODEL*2;       // 64 MB
  u16* wb = (u16*)(ws + off); off += (size_t)3*HD*DMODEL*2;     // 1.5 MB
  float2* tab = (float2*)(ws + off); off += (size_t)SEQ*64*8;   // 2 MB
  u16* qb = (u16*)(ws + off); off += (size_t)BS*HD*2;           // 4 MB
  u16* kb = (u16*)(ws + off); off += (size_t)BS*HD*2;           // 4 MB
  u16* vt = (u16*)(ws + off); off += (size_t)BS*HD*2;           // 4 MB
  float* Opart = (float*)(ws + off); off += (size_t)1024*64*HD*4; // 33.5 MB
  float2* ml   = (float2*)(ws + off); off += (size_t)1024*64*8;   // 0.5 MB
  if (ws_size < off) return;  // insufficient workspace -> fail visibly

  hipLaunchKernelGGL(k_tab,  dim3(1024),  dim3(256), 0, stream, tab);
  hipLaunchKernelGGL(k_cvtx, dim3(16384), dim3(256), 0, stream, x, xb);
  hipLaunchKernelGGL(k_cvtw, dim3(3072),  dim3(256), 0, stream, wq, wk, wv, wb);
  hipLaunchKernelGGL(k_gemm, dim3(128,3), dim3(256), 0, stream, xb, wb, tab, qb, kb, vt);
  hipLaunchKernelGGL(k_attn, dim3(1024),  dim3(256), 0, stream, qb, kb, vt, Opart, ml);
  hipLaunchKernelGGL(k_comb, dim3(2048),  dim3(256), 0, stream, Opart, ml, out);
}

// Round 4
// 130.104 us; speedup vs baseline: 2.8202x; 1.0641x over previous
//
#include <hip/hip_runtime.h>
#include <hip/hip_bf16.h>

#define BATCH 4
#define SEQ 4096
#define DMODEL 2048
#define HD 128
#define BS (BATCH*SEQ)

typedef __attribute__((ext_vector_type(8))) short short8;
typedef __attribute__((ext_vector_type(4))) float f32x4;
typedef __attribute__((ext_vector_type(4))) float float4v;
typedef unsigned short u16;
typedef unsigned int u32;

#define LOG2E 1.4426950408889634f
#define SCALE 0.08838834764831845f /* 1/sqrt(128) */

__device__ __forceinline__ u16 f2bf(float f){
  u32 u = __builtin_bit_cast(u32, f);
  u32 r = (u + 0x7FFFu + ((u >> 16) & 1u)) >> 16;
  return (u16)r;
}

__device__ __forceinline__ void gload16(const void* gptr, void* lptr){
  __builtin_amdgcn_global_load_lds((const __attribute__((address_space(1))) void*)gptr,
                                   (__attribute__((address_space(3))) void*)lptr, 16, 0, 0);
}

// ---------------- trig table: tab[s*64+j] = (cos, sin)(s * 10000^(-j/64)) ----------------
__global__ __launch_bounds__(256) void k_tab(float2* __restrict__ tab){
  int i = blockIdx.x*256 + threadIdx.x;      // 4096*64 total
  int s = i >> 6, j = i & 63;
  float invf = (float)pow(10000.0, -(double)j/64.0);
  float ang  = (float)s * invf;              // mimic fp32 reference rounding of the angle
  double a = (double)ang;
  tab[i] = make_float2((float)cos(a), (float)sin(a));
}

// ---------------- weights fp32 -> bf16 (wq|wk|wv packed) ----------------
__global__ __launch_bounds__(256) void k_cvtw(const float* __restrict__ wq, const float* __restrict__ wk,
                                              const float* __restrict__ wv, u16* __restrict__ wb){
  int i = blockIdx.x*256 + threadIdx.x;      // 3*262144 total
  int m = i >> 18; int r = i & 262143;
  const float* s = (m==0) ? wq : ((m==1) ? wk : wv);
  wb[i] = f2bf(s[r]);
}

// ---------------- fused QKV projection GEMM (fp32 x direct) + RoPE / V^T epilogue ----------
// grid 256: 64-row M-tile; block computes all 384 cols (Q|K|V). 4 waves split N:
// w0/w1 = Q rope-pairs + V[0..63], w2/w3 = K rope-pairs + V[64..127].
// LDS dbuf 2x(16KB fp32 A swizzled<<5 + 48KB bf16 W swizzled<<4) = 128KB.
__global__ __launch_bounds__(256) void k_gemm(
    const float* __restrict__ x, const u16* __restrict__ wb, const float2* __restrict__ tab,
    u16* __restrict__ qb, u16* __restrict__ kb, u16* __restrict__ vt)
{
  __shared__ char lds[2][65536];   // [0..16383]=lA fp32, [16384..65535]=lW bf16
  const int tid = threadIdx.x;
  const size_t M0 = (size_t)blockIdx.x * 64;
  const int w = tid >> 6, lane = tid & 63, lr = lane & 15, lg = lane >> 4;
  const int h = w & 1, g = w >> 1;

  // N-frag slots for this wave: [0..3] = rope pairs (lo0,hi0,lo1,hi1), [4..5] = V
  int nfs[6];
  nfs[0] = g*8 + 2*h;     nfs[1] = nfs[0] + 4;
  nfs[2] = g*8 + 2*h + 1; nfs[3] = nfs[2] + 4;
  nfs[4] = 16 + 2*w;      nfs[5] = nfs[4] + 1;

  // staging address precompute (element offsets sans k0)
  int aoff[4], adst[4], woff[12], wdst[12];
  #pragma unroll
  for (int i=0;i<4;i++){
    int L = i*4096 + tid*16;
    int row = L >> 8, cb = L & 255;
    int scb = cb ^ ((row & 7) << 5);
    aoff[i] = (int)((M0 + row)*DMODEL) + (scb >> 2);
    adst[i] = L;
  }
  #pragma unroll
  for (int i=0;i<12;i++){
    int L = i*4096 + tid*16;
    int row = L >> 7, cb = L & 127;
    int scb = cb ^ ((row & 7) << 4);
    woff[i] = row*DMODEL + (scb >> 1);
    wdst[i] = 16384 + L;
  }

  f32x4 acc[4][6];
  #pragma unroll
  for (int i=0;i<4;i++)
    #pragma unroll
    for (int j=0;j<6;j++) acc[i][j] = f32x4{0.f,0.f,0.f,0.f};

  // prologue stage
  {
    char* base = lds[0];
    #pragma unroll
    for (int i=0;i<4;i++)  gload16(x + aoff[i], base + adst[i]);
    #pragma unroll
    for (int i=0;i<12;i++) gload16(wb + woff[i], base + wdst[i]);
  }
  __syncthreads();

  int cur = 0;
  for (int t=0; t<32; t++){
    if (t < 31){
      char* base = lds[cur^1];
      const int k0 = (t+1)*64;
      #pragma unroll
      for (int i=0;i<4;i++)  gload16(x + aoff[i] + k0, base + adst[i]);
      #pragma unroll
      for (int i=0;i<12;i++) gload16(wb + woff[i] + k0, base + wdst[i]);
    }
    const char* lA = lds[cur];
    const char* lW = lds[cur] + 16384;

    short8 af[2][4];
    #pragma unroll
    for (int ks=0;ks<2;ks++)
      #pragma unroll
      for (int rf=0;rf<4;rf++){
        int r = rf*16 + lr;
        int byte = r*256 + ((ks*128 + lg*32) ^ ((r&7)<<5));
        f32x4 va = *(const f32x4*)(lA + byte);
        f32x4 vb = *(const f32x4*)(lA + byte + 16);
        short8 tt;
        tt[0]=(short)f2bf(va[0]); tt[1]=(short)f2bf(va[1]); tt[2]=(short)f2bf(va[2]); tt[3]=(short)f2bf(va[3]);
        tt[4]=(short)f2bf(vb[0]); tt[5]=(short)f2bf(vb[1]); tt[6]=(short)f2bf(vb[2]); tt[7]=(short)f2bf(vb[3]);
        af[ks][rf] = tt;
      }
    #pragma unroll
    for (int j=0;j<6;j++){
      int rw = nfs[j]*16 + lr;
      #pragma unroll
      for (int ks=0;ks<2;ks++){
        int byte = rw*128 + ((ks*64 + lg*16) ^ ((lr&7)<<4));
        short8 bf = *(const short8*)(lW + byte);
        #pragma unroll
        for (int rf=0;rf<4;rf++)
          acc[rf][j] = __builtin_amdgcn_mfma_f32_16x16x32_bf16(af[ks][rf], bf, acc[rf][j], 0,0,0);
      }
    }
    __syncthreads();
    cur ^= 1;
  }

  // epilogue: RoPE on Q/K pairs, V transposed store
  u16* dst = (g == 0) ? qb : kb;
  #pragma unroll
  for (int rf=0; rf<4; rf++)
    #pragma unroll
    for (int reg=0; reg<4; reg++){
      size_t grow = M0 + rf*16 + lg*4 + reg;
      int spos = (int)(grow & (SEQ-1));
      size_t b = grow >> 12;
      #pragma unroll
      for (int p=0; p<2; p++){
        int j = (2*h + p)*16 + lr;
        float2 cs = tab[spos*64 + j];
        float lo = acc[rf][2*p][reg];
        float hi = acc[rf][2*p+1][reg];
        dst[grow*HD + j]      = f2bf(lo*cs.x - hi*cs.y);
        dst[grow*HD + j + 64] = f2bf(hi*cs.x + lo*cs.y);
      }
      #pragma unroll
      for (int jj=0; jj<2; jj++){
        int col = (2*w + jj)*16 + lr;
        vt[(b*HD + col)*SEQ + spos] = f2bf(acc[rf][4+jj][reg]);
      }
    }
}

// ---------------- causal flash attention, 4-way KV split (flash-decoding) ----------------
// grid 1024: (batch, 64-row q-tile, kv-split). 4 waves x 16 q-rows share staged lK/lV.
// LDS 40KB -> 4 blocks/CU -> 16 waves/CU. qt descending (heavy first);
// bid&7 -> XCD pairs per batch so each XCD's L2 holds one batch's K+V (2MB).
__global__ __launch_bounds__(256) void k_attn(
    const u16* __restrict__ qbuf, const u16* __restrict__ kb, const u16* __restrict__ vt,
    float* __restrict__ Opart, float2* __restrict__ ml)
{
  __shared__ u16 lK[64*128];    // byte = kv*256 + (cb ^ ((kv&7)<<4))
  __shared__ u16 lV[128*64];    // byte = d*128  + (cb ^ ((d&7)<<4))
  __shared__ u16 lP[4][16*64];  // per-wave, byte = r*128 + (cb ^ ((r&7)<<4))
  const int tid = threadIdx.x;
  const int bid = blockIdx.x;
  const int x = bid & 7, idx = bid >> 3;
  const int b = x >> 1, half = x & 1;
  const int qt = 63 - (idx >> 1);              // heavy tiles first
  const int sp = (idx & 1) + 2*half;           // kv-split 0..3
  const int qbn = b*64 + qt;                   // 0..255
  const int w = tid >> 6, lane = tid & 63, lr = lane & 15, lg = lane >> 4;

  // balanced contiguous partition of tiles [0, qt] into 4 chunks
  const int n = qt + 1, cbase = n >> 2, crem = n & 3;
  const int cnt = cbase + (sp < crem ? 1 : 0);
  const int klo = sp*cbase + (sp < crem ? sp : crem);
  const int khi = klo + cnt;
  const size_t prow0 = ((size_t)qbn*4 + sp)*64;

  if (cnt == 0){                               // empty split: mark and exit (block-uniform)
    if (lr == 0){
      #pragma unroll
      for (int reg=0; reg<4; reg++)
        ml[prow0 + w*16 + lg*4 + reg] = make_float2(-1e30f, 0.f);
    }
    return;
  }

  const size_t qrow = (size_t)b*SEQ + qt*64 + w*16 + lr;
  short8 aq[4];
  #pragma unroll
  for (int ks=0; ks<4; ks++)
    aq[ks] = *(const short8*)(qbuf + qrow*HD + ks*32 + lg*8);

  f32x4 accO[8];
  #pragma unroll
  for (int i=0;i<8;i++) accO[i] = f32x4{0.f,0.f,0.f,0.f};
  float m2[4]   = {-1e30f,-1e30f,-1e30f,-1e30f};
  float lsum[4] = {0.f,0.f,0.f,0.f};

  const int Lb = tid*16;
  const float cfac = SCALE * LOG2E;

  for (int kt = klo; kt < khi; kt++){
    #pragma unroll
    for (int i=0;i<4;i++){
      int L = i*4096 + Lb;
      { int row = L >> 8, cb = L & 255;
        int scb = cb ^ ((row & 7) << 4);
        gload16(kb + ((size_t)b*SEQ + kt*64 + row)*HD + (scb>>1), ((char*)lK) + L); }
      { int row = L >> 7, cb = L & 127;
        int scb = cb ^ ((row & 7) << 4);
        gload16(vt + ((size_t)b*HD + row)*SEQ + kt*64 + (scb>>1), ((char*)lV) + L); }
    }
    __syncthreads();

    // S = Q K^T  (16 q-rows x 64 kv) in log2-domain units
    f32x4 sc[4];
    #pragma unroll
    for (int nf=0; nf<4; nf++){
      sc[nf] = f32x4{0.f,0.f,0.f,0.f};
      #pragma unroll
      for (int ks=0; ks<4; ks++){
        int r = nf*16 + lr;
        int byte = r*256 + ((ks*64 + lg*16) ^ ((r&7)<<4));
        short8 bk = *(const short8*)((const char*)lK + byte);
        sc[nf] = __builtin_amdgcn_mfma_f32_16x16x32_bf16(aq[ks], bk, sc[nf], 0,0,0);
      }
      sc[nf] *= cfac;
    }
    if (kt == qt){                            // diagonal tile: causal mask
      #pragma unroll
      for (int nf=0; nf<4; nf++)
        #pragma unroll
        for (int reg=0; reg<4; reg++){
          int col = nf*16 + lr;
          int row = w*16 + lg*4 + reg;
          if (col > row) sc[nf][reg] = -1e30f;
        }
    }
    float al[4];
    #pragma unroll
    for (int reg=0; reg<4; reg++){
      float v = fmaxf(fmaxf(sc[0][reg], sc[1][reg]), fmaxf(sc[2][reg], sc[3][reg]));
      v = fmaxf(v, __shfl_xor(v, 1));
      v = fmaxf(v, __shfl_xor(v, 2));
      v = fmaxf(v, __shfl_xor(v, 4));
      v = fmaxf(v, __shfl_xor(v, 8));
      float mnew = fmaxf(m2[reg], v);
      al[reg] = exp2f(m2[reg] - mnew);
      m2[reg] = mnew;
    }
    float prs[4] = {0.f,0.f,0.f,0.f};
    #pragma unroll
    for (int nf=0; nf<4; nf++)
      #pragma unroll
      for (int reg=0; reg<4; reg++){
        float p = exp2f(sc[nf][reg] - m2[reg]);
        prs[reg] += p;
        int r = lg*4 + reg;
        int byte = r*128 + ((nf*32 + lr*2) ^ ((r&7)<<4));
        *(u16*)(((char*)lP[w]) + byte) = f2bf(p);
      }
    f32x4 alv = f32x4{al[0], al[1], al[2], al[3]};
    #pragma unroll
    for (int reg=0; reg<4; reg++){
      float v = prs[reg];
      v += __shfl_xor(v, 1);
      v += __shfl_xor(v, 2);
      v += __shfl_xor(v, 4);
      v += __shfl_xor(v, 8);
      lsum[reg] = lsum[reg]*al[reg] + v;
    }
    #pragma unroll
    for (int cf=0; cf<8; cf++) accO[cf] *= alv;

    short8 pa[2];
    #pragma unroll
    for (int ks=0; ks<2; ks++){
      int byte = lr*128 + ((ks*64 + lg*16) ^ ((lr&7)<<4));
      pa[ks] = *(const short8*)(((const char*)lP[w]) + byte);
    }
    #pragma unroll
    for (int cf=0; cf<8; cf++){
      #pragma unroll
      for (int ks=0; ks<2; ks++){
        int d = cf*16 + lr;
        int byte = d*128 + ((ks*64 + lg*16) ^ ((d&7)<<4));
        short8 bv = *(const short8*)(((const char*)lV) + byte);
        accO[cf] = __builtin_amdgcn_mfma_f32_16x16x32_bf16(pa[ks], bv, accO[cf], 0,0,0);
      }
    }
    __syncthreads();
  }

  // partial epilogue: raw accO + (m, l) per row
  #pragma unroll
  for (int reg=0; reg<4; reg++){
    size_t pr = prow0 + w*16 + lg*4 + reg;
    #pragma unroll
    for (int cf=0; cf<8; cf++)
      Opart[pr*HD + cf*16 + lr] = accO[cf][reg];
  }
  if (lr == 0){
    #pragma unroll
    for (int reg=0; reg<4; reg++)
      ml[prow0 + w*16 + lg*4 + reg] = make_float2(m2[reg], lsum[reg]);
  }
}

// ---------------- combine partials: out = sum_s O_s * 2^(m_s-M) / L ----------------
__global__ __launch_bounds__(256) void k_comb(
    const float* __restrict__ Opart, const float2* __restrict__ ml, float* __restrict__ out)
{
  const int t = threadIdx.x;
  const int r = blockIdx.x*8 + (t >> 5);       // global row 0..16383
  const int c = (t & 31)*4;
  const int qbn = r >> 6, rr = r & 63;
  float m[4], l[4], M = -1e30f;
  #pragma unroll
  for (int s=0; s<4; s++){
    float2 v = ml[((size_t)qbn*4 + s)*64 + rr];
    m[s] = v.x; l[s] = v.y;
    M = fmaxf(M, m[s]);
  }
  float L = 0.f;
  #pragma unroll
  for (int s=0; s<4; s++){ m[s] = exp2f(m[s] - M); L += l[s]*m[s]; }
  const float inv = 1.0f / L;
  f32x4 acc = f32x4{0.f,0.f,0.f,0.f};
  #pragma unroll
  for (int s=0; s<4; s++){
    f32x4 o = *(const f32x4*)(Opart + (((size_t)qbn*4 + s)*64 + rr)*(size_t)HD + c);
    float sc = m[s]*inv;
    acc += o * sc;
  }
  *(f32x4*)(out + (size_t)r*HD + c) = acc;
}

extern "C" void kernel_launch(void* const* d_in, const int* in_sizes, int n_in,
                              void* d_out, int out_size, void* d_ws, size_t ws_size,
                              hipStream_t stream){
  const float* x  = (const float*)d_in[0];
  const float* wq = (const float*)d_in[1];
  const float* wk = (const float*)d_in[2];
  const float* wv = (const float*)d_in[3];
  float* out = (float*)d_out;
  char* ws = (char*)d_ws;

  size_t off = 0;
  u16* wb = (u16*)(ws + off); off += (size_t)3*HD*DMODEL*2;     // 1.5 MB
  float2* tab = (float2*)(ws + off); off += (size_t)SEQ*64*8;   // 2 MB
  u16* qb = (u16*)(ws + off); off += (size_t)BS*HD*2;           // 4 MB
  u16* kb = (u16*)(ws + off); off += (size_t)BS*HD*2;           // 4 MB
  u16* vt = (u16*)(ws + off); off += (size_t)BS*HD*2;           // 4 MB
  float* Opart = (float*)(ws + off); off += (size_t)1024*64*HD*4; // 33.5 MB
  float2* ml   = (float2*)(ws + off); off += (size_t)1024*64*8;   // 0.5 MB
  if (ws_size < off) return;  // insufficient workspace -> fail visibly

  hipLaunchKernelGGL(k_tab,  dim3(1024),  dim3(256), 0, stream, tab);
  hipLaunchKernelGGL(k_cvtw, dim3(3072),  dim3(256), 0, stream, wq, wk, wv, wb);
  hipLaunchKernelGGL(k_gemm, dim3(256),   dim3(256), 0, stream, x, wb, tab, qb, kb, vt);
  hipLaunchKernelGGL(k_attn, dim3(1024),  dim3(256), 0, stream, qb, kb, vt, Opart, ml);
  hipLaunchKernelGGL(k_comb, dim3(2048),  dim3(256), 0, stream, Opart, ml, out);
}

// Round 6
// 127.690 us; speedup vs baseline: 2.8735x; 1.0189x over previous
//
#include <hip/hip_runtime.h>
#include <hip/hip_bf16.h>

#define BATCH 4
#define SEQ 4096
#define DMODEL 2048
#define HD 128
#define BS (BATCH*SEQ)

typedef __attribute__((ext_vector_type(8))) short short8;
typedef __attribute__((ext_vector_type(4))) float f32x4;
typedef __attribute__((ext_vector_type(4))) float float4v;
typedef unsigned short u16;
typedef unsigned int u32;

#define LOG2E 1.4426950408889634f
#define SCALE 0.08838834764831845f /* 1/sqrt(128) */

__device__ __forceinline__ u16 f2bf(float f){
  u32 u = __builtin_bit_cast(u32, f);
  u32 r = (u + 0x7FFFu + ((u >> 16) & 1u)) >> 16;
  return (u16)r;
}

__device__ __forceinline__ void gload16(const void* gptr, void* lptr){
  __builtin_amdgcn_global_load_lds((const __attribute__((address_space(1))) void*)gptr,
                                   (__attribute__((address_space(3))) void*)lptr, 16, 0, 0);
}

// ---------------- trig table: tab[s*64+j] = (cos, sin)(s * 10000^(-j/64)) ----------------
__global__ __launch_bounds__(256) void k_tab(float2* __restrict__ tab){
  int i = blockIdx.x*256 + threadIdx.x;      // 4096*64 total
  int s = i >> 6, j = i & 63;
  float invf = (float)pow(10000.0, -(double)j/64.0);
  float ang  = (float)s * invf;              // mimic fp32 reference rounding of the angle
  double a = (double)ang;
  tab[i] = make_float2((float)cos(a), (float)sin(a));
}

// ---------------- weights fp32 -> bf16 (wq|wk|wv packed) ----------------
__global__ __launch_bounds__(256) void k_cvtw(const float* __restrict__ wq, const float* __restrict__ wk,
                                              const float* __restrict__ wv, u16* __restrict__ wb){
  int i = blockIdx.x*256 + threadIdx.x;      // 3*262144 total
  int m = i >> 18; int r = i & 262143;
  const float* s = (m==0) ? wq : ((m==1) ? wk : wv);
  wb[i] = f2bf(s[r]);
}

// ---------------- fused QKV projection GEMM (fp32 x read once) + RoPE / V^T epilogue ------
// grid 512: 32-row M-tile, all 384 cols (Q|K|V). 4 waves, each 32 rows x 96 cols.
// LDS 56KB (A bf16 dbuf 2x4KB + W 48KB single-buf) -> 2 blocks/CU, 8 waves/CU.
// RACE FIX (r5): issue order per iter is now W-then-A, so vmcnt(2) retires all 12 W
// global_load_lds and leaves only the 2 newest A-prefetch loads in flight.
// sched_barrier(0) pins every phase boundary so the compiler can't reorder issues.
__global__ __launch_bounds__(256) void k_gemm(
    const float* __restrict__ x, const u16* __restrict__ wb, const float2* __restrict__ tab,
    u16* __restrict__ qb, u16* __restrict__ kb, u16* __restrict__ vt)
{
  __shared__ char lds[8192 + 49152];   // [0..8191] A dbuf (2x4KB), [8192..] W 48KB
  const int tid = threadIdx.x;
  const size_t M0 = (size_t)blockIdx.x * 32;
  const int w = tid >> 6, lane = tid & 63, lr = lane & 15, lg = lane >> 4;
  const int h = w & 1, g = w >> 1;

  // N-frag slots: [0..3] = rope pairs (lo0,hi0,lo1,hi1), [4..5] = V
  int nfs[6];
  nfs[0] = g*8 + 2*h;     nfs[1] = nfs[0] + 4;
  nfs[2] = g*8 + 2*h + 1; nfs[3] = nfs[2] + 4;
  nfs[4] = 16 + 2*w;      nfs[5] = nfs[4] + 1;

  // A staging: thread handles 8 consecutive fp32 of the 32x64 tile
  const int arow = tid >> 3, acol = (tid & 7)*8;
  const float* axp = x + (M0 + arow)*DMODEL + acol;
  const int awbyte = arow*128 + ((acol*2) ^ ((arow & 7) << 4));

  // W staging: 12 gload16/thread, preswizzled source
  int woff[12], wdst[12];
  #pragma unroll
  for (int i=0;i<12;i++){
    int L = i*4096 + tid*16;
    int row = L >> 7, cb = L & 127;
    int scb = cb ^ ((row & 7) << 4);
    woff[i] = row*DMODEL + (scb >> 1);
    wdst[i] = 8192 + L;
  }

  f32x4 acc[2][6];
  #pragma unroll
  for (int i=0;i<2;i++)
    #pragma unroll
    for (int j=0;j<6;j++) acc[i][j] = f32x4{0.f,0.f,0.f,0.f};

  float4v s0a, s0b, s1a, s1b;   // prefetch slots (tile parity 0 / 1)

  // ---- prologue: A(0); W(0); A(1); cvt A(0); vmcnt(2) leaves A(1) in flight ----
  s0a = *(const float4v*)(axp);      s0b = *(const float4v*)(axp + 4);
  __builtin_amdgcn_sched_barrier(0);
  #pragma unroll
  for (int i=0;i<12;i++) gload16(wb + woff[i], lds + wdst[i]);
  __builtin_amdgcn_sched_barrier(0);
  s1a = *(const float4v*)(axp + 64); s1b = *(const float4v*)(axp + 68);
  __builtin_amdgcn_sched_barrier(0);
  {
    short8 o;
    o[0]=(short)f2bf(s0a[0]); o[1]=(short)f2bf(s0a[1]); o[2]=(short)f2bf(s0a[2]); o[3]=(short)f2bf(s0a[3]);
    o[4]=(short)f2bf(s0b[0]); o[5]=(short)f2bf(s0b[1]); o[6]=(short)f2bf(s0b[2]); o[7]=(short)f2bf(s0b[3]);
    *(short8*)(lds + awbyte) = o;
  }
  __builtin_amdgcn_sched_barrier(0);
  asm volatile("s_waitcnt vmcnt(2) lgkmcnt(0)" ::: "memory");
  __builtin_amdgcn_sched_barrier(0);
  __builtin_amdgcn_s_barrier();
  __builtin_amdgcn_sched_barrier(0);

  for (int t=0; t<31; t++){
    const int p = t & 1;
    // [2] compute tile t from bufA[p] + W(t)
    {
      const char* lA = lds + p*4096;
      const char* lW = lds + 8192;
      short8 af[2][2];
      #pragma unroll
      for (int ks=0;ks<2;ks++)
        #pragma unroll
        for (int rf=0;rf<2;rf++){
          int r = rf*16 + lr;
          af[ks][rf] = *(const short8*)(lA + r*128 + ((ks*64 + lg*16) ^ ((r&7)<<4)));
        }
      #pragma unroll
      for (int j=0;j<6;j++){
        int rw = nfs[j]*16 + lr;
        #pragma unroll
        for (int ks=0;ks<2;ks++){
          short8 bf = *(const short8*)(lW + rw*128 + ((ks*64 + lg*16) ^ ((lr&7)<<4)));
          #pragma unroll
          for (int rf=0;rf<2;rf++)
            acc[rf][j] = __builtin_amdgcn_mfma_f32_16x16x32_bf16(af[ks][rf], bf, acc[rf][j], 0,0,0);
        }
      }
    }
    // [3] all waves done reading W(t) and bufA[p]
    __builtin_amdgcn_sched_barrier(0);
    __builtin_amdgcn_s_barrier();
    __builtin_amdgcn_sched_barrier(0);
    // [4] issue W(t+1)  (12 global_load_lds — must be OLDER than the A prefetch)
    const int k0 = (t+1)*64;
    #pragma unroll
    for (int i=0;i<12;i++) gload16(wb + woff[i] + k0, lds + wdst[i]);
    __builtin_amdgcn_sched_barrier(0);
    // [1'] issue A(t+2) into slot p (clamped at the tail; redundancy keeps vmcnt uniform)
    {
      const float* ap = axp + (t+2 <= 31 ? (t+2)*64 : 31*64);
      float4v na = *(const float4v*)(ap), nb = *(const float4v*)(ap + 4);
      if (p == 0){ s0a = na; s0b = nb; } else { s1a = na; s1b = nb; }
    }
    __builtin_amdgcn_sched_barrier(0);
    // [5] cvt A(t+1) (slot p^1; compiler auto-waits those oldest loads) -> bufA[p^1]
    {
      float4v ca, cb2;
      if (p == 0){ ca = s1a; cb2 = s1b; } else { ca = s0a; cb2 = s0b; }
      short8 o;
      o[0]=(short)f2bf(ca[0]);  o[1]=(short)f2bf(ca[1]);  o[2]=(short)f2bf(ca[2]);  o[3]=(short)f2bf(ca[3]);
      o[4]=(short)f2bf(cb2[0]); o[5]=(short)f2bf(cb2[1]); o[6]=(short)f2bf(cb2[2]); o[7]=(short)f2bf(cb2[3]);
      *(short8*)(lds + (p^1)*4096 + awbyte) = o;
    }
    __builtin_amdgcn_sched_barrier(0);
    // [6] W(t+1) + ds_writes complete; only A(t+2)'s 2 loads stay in flight
    asm volatile("s_waitcnt vmcnt(2) lgkmcnt(0)" ::: "memory");
    __builtin_amdgcn_sched_barrier(0);
    __builtin_amdgcn_s_barrier();
    __builtin_amdgcn_sched_barrier(0);
  }
  // final tile 31 compute
  {
    const char* lA = lds + (31 & 1)*4096;
    const char* lW = lds + 8192;
    short8 af[2][2];
    #pragma unroll
    for (int ks=0;ks<2;ks++)
      #pragma unroll
      for (int rf=0;rf<2;rf++){
        int r = rf*16 + lr;
        af[ks][rf] = *(const short8*)(lA + r*128 + ((ks*64 + lg*16) ^ ((r&7)<<4)));
      }
    #pragma unroll
    for (int j=0;j<6;j++){
      int rw = nfs[j]*16 + lr;
      #pragma unroll
      for (int ks=0;ks<2;ks++){
        short8 bf = *(const short8*)(lW + rw*128 + ((ks*64 + lg*16) ^ ((lr&7)<<4)));
        #pragma unroll
        for (int rf=0;rf<2;rf++)
          acc[rf][j] = __builtin_amdgcn_mfma_f32_16x16x32_bf16(af[ks][rf], bf, acc[rf][j], 0,0,0);
      }
    }
  }

  // epilogue: RoPE on Q/K pairs, V transposed store
  u16* dst = (g == 0) ? qb : kb;
  #pragma unroll
  for (int rf=0; rf<2; rf++)
    #pragma unroll
    for (int reg=0; reg<4; reg++){
      size_t grow = M0 + rf*16 + lg*4 + reg;
      int spos = (int)(grow & (SEQ-1));
      size_t b = grow >> 12;
      #pragma unroll
      for (int p=0; p<2; p++){
        int j = (2*h + p)*16 + lr;
        float2 cs = tab[spos*64 + j];
        float lo = acc[rf][2*p][reg];
        float hi = acc[rf][2*p+1][reg];
        dst[grow*HD + j]      = f2bf(lo*cs.x - hi*cs.y);
        dst[grow*HD + j + 64] = f2bf(hi*cs.x + lo*cs.y);
      }
      #pragma unroll
      for (int jj=0; jj<2; jj++){
        int col = (2*w + jj)*16 + lr;
        vt[(b*HD + col)*SEQ + spos] = f2bf(acc[rf][4+jj][reg]);
      }
    }
}

// ---------------- causal flash attention, 4-way KV split (flash-decoding) ----------------
// grid 1024: (batch, 64-row q-tile, kv-split). 4 waves x 16 q-rows share staged lK/lV.
// LDS 40KB -> 4 blocks/CU -> 16 waves/CU. qt descending (heavy first);
// bid&7 -> XCD pairs per batch so each XCD's L2 holds one batch's K+V (2MB).
__global__ __launch_bounds__(256) void k_attn(
    const u16* __restrict__ qbuf, const u16* __restrict__ kb, const u16* __restrict__ vt,
    float* __restrict__ Opart, float2* __restrict__ ml)
{
  __shared__ u16 lK[64*128];    // byte = kv*256 + (cb ^ ((kv&7)<<4))
  __shared__ u16 lV[128*64];    // byte = d*128  + (cb ^ ((d&7)<<4))
  __shared__ u16 lP[4][16*64];  // per-wave, byte = r*128 + (cb ^ ((r&7)<<4))
  const int tid = threadIdx.x;
  const int bid = blockIdx.x;
  const int x = bid & 7, idx = bid >> 3;
  const int b = x >> 1, half = x & 1;
  const int qt = 63 - (idx >> 1);              // heavy tiles first
  const int sp = (idx & 1) + 2*half;           // kv-split 0..3
  const int qbn = b*64 + qt;                   // 0..255
  const int w = tid >> 6, lane = tid & 63, lr = lane & 15, lg = lane >> 4;

  // balanced contiguous partition of tiles [0, qt] into 4 chunks
  const int n = qt + 1, cbase = n >> 2, crem = n & 3;
  const int cnt = cbase + (sp < crem ? 1 : 0);
  const int klo = sp*cbase + (sp < crem ? sp : crem);
  const int khi = klo + cnt;
  const size_t prow0 = ((size_t)qbn*4 + sp)*64;

  if (cnt == 0){                               // empty split: mark and exit (block-uniform)
    if (lr == 0){
      #pragma unroll
      for (int reg=0; reg<4; reg++)
        ml[prow0 + w*16 + lg*4 + reg] = make_float2(-1e30f, 0.f);
    }
    return;
  }

  const size_t qrow = (size_t)b*SEQ + qt*64 + w*16 + lr;
  short8 aq[4];
  #pragma unroll
  for (int ks=0; ks<4; ks++)
    aq[ks] = *(const short8*)(qbuf + qrow*HD + ks*32 + lg*8);

  f32x4 accO[8];
  #pragma unroll
  for (int i=0;i<8;i++) accO[i] = f32x4{0.f,0.f,0.f,0.f};
  float m2[4]   = {-1e30f,-1e30f,-1e30f,-1e30f};
  float lsum[4] = {0.f,0.f,0.f,0.f};

  const int Lb = tid*16;
  const float cfac = SCALE * LOG2E;

  for (int kt = klo; kt < khi; kt++){
    #pragma unroll
    for (int i=0;i<4;i++){
      int L = i*4096 + Lb;
      { int row = L >> 8, cb = L & 255;
        int scb = cb ^ ((row & 7) << 4);
        gload16(kb + ((size_t)b*SEQ + kt*64 + row)*HD + (scb>>1), ((char*)lK) + L); }
      { int row = L >> 7, cb = L & 127;
        int scb = cb ^ ((row & 7) << 4);
        gload16(vt + ((size_t)b*HD + row)*SEQ + kt*64 + (scb>>1), ((char*)lV) + L); }
    }
    __syncthreads();

    // S = Q K^T  (16 q-rows x 64 kv) in log2-domain units
    f32x4 sc[4];
    #pragma unroll
    for (int nf=0; nf<4; nf++){
      sc[nf] = f32x4{0.f,0.f,0.f,0.f};
      #pragma unroll
      for (int ks=0; ks<4; ks++){
        int r = nf*16 + lr;
        int byte = r*256 + ((ks*64 + lg*16) ^ ((r&7)<<4));
        short8 bk = *(const short8*)((const char*)lK + byte);
        sc[nf] = __builtin_amdgcn_mfma_f32_16x16x32_bf16(aq[ks], bk, sc[nf], 0,0,0);
      }
      sc[nf] *= cfac;
    }
    if (kt == qt){                            // diagonal tile: causal mask
      #pragma unroll
      for (int nf=0; nf<4; nf++)
        #pragma unroll
        for (int reg=0; reg<4; reg++){
          int col = nf*16 + lr;
          int row = w*16 + lg*4 + reg;
          if (col > row) sc[nf][reg] = -1e30f;
        }
    }
    float al[4];
    #pragma unroll
    for (int reg=0; reg<4; reg++){
      float v = fmaxf(fmaxf(sc[0][reg], sc[1][reg]), fmaxf(sc[2][reg], sc[3][reg]));
      v = fmaxf(v, __shfl_xor(v, 1));
      v = fmaxf(v, __shfl_xor(v, 2));
      v = fmaxf(v, __shfl_xor(v, 4));
      v = fmaxf(v, __shfl_xor(v, 8));
      float mnew = fmaxf(m2[reg], v);
      al[reg] = exp2f(m2[reg] - mnew);
      m2[reg] = mnew;
    }
    float prs[4] = {0.f,0.f,0.f,0.f};
    #pragma unroll
    for (int nf=0; nf<4; nf++)
      #pragma unroll
      for (int reg=0; reg<4; reg++){
        float p = exp2f(sc[nf][reg] - m2[reg]);
        prs[reg] += p;
        int r = lg*4 + reg;
        int byte = r*128 + ((nf*32 + lr*2) ^ ((r&7)<<4));
        *(u16*)(((char*)lP[w]) + byte) = f2bf(p);
      }
    f32x4 alv = f32x4{al[0], al[1], al[2], al[3]};
    #pragma unroll
    for (int reg=0; reg<4; reg++){
      float v = prs[reg];
      v += __shfl_xor(v, 1);
      v += __shfl_xor(v, 2);
      v += __shfl_xor(v, 4);
      v += __shfl_xor(v, 8);
      lsum[reg] = lsum[reg]*al[reg] + v;
    }
    #pragma unroll
    for (int cf=0; cf<8; cf++) accO[cf] *= alv;

    short8 pa[2];
    #pragma unroll
    for (int ks=0; ks<2; ks++){
      int byte = lr*128 + ((ks*64 + lg*16) ^ ((lr&7)<<4));
      pa[ks] = *(const short8*)(((const char*)lP[w]) + byte);
    }
    #pragma unroll
    for (int cf=0; cf<8; cf++){
      #pragma unroll
      for (int ks=0; ks<2; ks++){
        int d = cf*16 + lr;
        int byte = d*128 + ((ks*64 + lg*16) ^ ((d&7)<<4));
        short8 bv = *(const short8*)(((const char*)lV) + byte);
        accO[cf] = __builtin_amdgcn_mfma_f32_16x16x32_bf16(pa[ks], bv, accO[cf], 0,0,0);
      }
    }
    __syncthreads();
  }

  // partial epilogue: raw accO + (m, l) per row
  #pragma unroll
  for (int reg=0; reg<4; reg++){
    size_t pr = prow0 + w*16 + lg*4 + reg;
    #pragma unroll
    for (int cf=0; cf<8; cf++)
      Opart[pr*HD + cf*16 + lr] = accO[cf][reg];
  }
  if (lr == 0){
    #pragma unroll
    for (int reg=0; reg<4; reg++)
      ml[prow0 + w*16 + lg*4 + reg] = make_float2(m2[reg], lsum[reg]);
  }
}

// ---------------- combine partials: out = sum_s O_s * 2^(m_s-M) / L ----------------
__global__ __launch_bounds__(256) void k_comb(
    const float* __restrict__ Opart, const float2* __restrict__ ml, float* __restrict__ out)
{
  const int t = threadIdx.x;
  const int r = blockIdx.x*8 + (t >> 5);       // global row 0..16383
  const int c = (t & 31)*4;
  const int qbn = r >> 6, rr = r & 63;
  float m[4], l[4], M = -1e30f;
  #pragma unroll
  for (int s=0; s<4; s++){
    float2 v = ml[((size_t)qbn*4 + s)*64 + rr];
    m[s] = v.x; l[s] = v.y;
    M = fmaxf(M, m[s]);
  }
  float L = 0.f;
  #pragma unroll
  for (int s=0; s<4; s++){ m[s] = exp2f(m[s] - M); L += l[s]*m[s]; }
  const float inv = 1.0f / L;
  f32x4 acc = f32x4{0.f,0.f,0.f,0.f};
  #pragma unroll
  for (int s=0; s<4; s++){
    f32x4 o = *(const f32x4*)(Opart + (((size_t)qbn*4 + s)*64 + rr)*(size_t)HD + c);
    float sc = m[s]*inv;
    acc += o * sc;
  }
  *(f32x4*)(out + (size_t)r*HD + c) = acc;
}

extern "C" void kernel_launch(void* const* d_in, const int* in_sizes, int n_in,
                              void* d_out, int out_size, void* d_ws, size_t ws_size,
                              hipStream_t stream){
  const float* x  = (const float*)d_in[0];
  const float* wq = (const float*)d_in[1];
  const float* wk = (const float*)d_in[2];
  const float* wv = (const float*)d_in[3];
  float* out = (float*)d_out;
  char* ws = (char*)d_ws;

  size_t off = 0;
  u16* wb = (u16*)(ws + off); off += (size_t)3*HD*DMODEL*2;     // 1.5 MB
  float2* tab = (float2*)(ws + off); off += (size_t)SEQ*64*8;   // 2 MB
  u16* qb = (u16*)(ws + off); off += (size_t)BS*HD*2;           // 4 MB
  u16* kb = (u16*)(ws + off); off += (size_t)BS*HD*2;           // 4 MB
  u16* vt = (u16*)(ws + off); off += (size_t)BS*HD*2;           // 4 MB
  float* Opart = (float*)(ws + off); off += (size_t)1024*64*HD*4; // 33.5 MB
  float2* ml   = (float2*)(ws + off); off += (size_t)1024*64*8;   // 0.5 MB
  if (ws_size < off) return;  // insufficient workspace -> fail visibly

  hipLaunchKernelGGL(k_tab,  dim3(1024),  dim3(256), 0, stream, tab);
  hipLaunchKernelGGL(k_cvtw, dim3(3072),  dim3(256), 0, stream, wq, wk, wv, wb);
  hipLaunchKernelGGL(k_gemm, dim3(512),   dim3(256), 0, stream, x, wb, tab, qb, kb, vt);
  hipLaunchKernelGGL(k_attn, dim3(1024),  dim3(256), 0, stream, qb, kb, vt, Opart, ml);
  hipLaunchKernelGGL(k_comb, dim3(2048),  dim3(256), 0, stream, Opart, ml, out);
}

// Round 7
// 116.408 us; speedup vs baseline: 3.1520x; 1.0969x over previous
//
#include <hip/hip_runtime.h>
#include <hip/hip_bf16.h>

#define BATCH 4
#define SEQ 4096
#define DMODEL 2048
#define HD 128
#define BS (BATCH*SEQ)

typedef __attribute__((ext_vector_type(8))) short short8;
typedef __attribute__((ext_vector_type(4))) float f32x4;
typedef __attribute__((ext_vector_type(4))) float float4v;
typedef unsigned short u16;
typedef unsigned int u32;

#define LOG2E 1.4426950408889634f
#define SCALE 0.08838834764831845f /* 1/sqrt(128) */

__device__ __forceinline__ u16 f2bf(float f){
  u32 u = __builtin_bit_cast(u32, f);
  u32 r = (u + 0x7FFFu + ((u >> 16) & 1u)) >> 16;
  return (u16)r;
}

__device__ __forceinline__ void gload16(const void* gptr, void* lptr){
  __builtin_amdgcn_global_load_lds((const __attribute__((address_space(1))) void*)gptr,
                                   (__attribute__((address_space(3))) void*)lptr, 16, 0, 0);
}

// ---------------- trig table: tab[s*64+j] = (cos, sin)(s * 10000^(-j/64)) ----------------
__global__ __launch_bounds__(256) void k_tab(float2* __restrict__ tab){
  int i = blockIdx.x*256 + threadIdx.x;      // 4096*64 total
  int s = i >> 6, j = i & 63;
  float invf = (float)pow(10000.0, -(double)j/64.0);
  float ang  = (float)s * invf;              // mimic fp32 reference rounding of the angle
  double a = (double)ang;
  tab[i] = make_float2((float)cos(a), (float)sin(a));
}

// ---------------- weights fp32 -> bf16, packed [Q(128) | V:0-63 | K(128) | V:64-127] ------
// Row layout lets the gemm's 2 N-groups (192 rows each) hold complete RoPE pairs:
// ng=0 -> full Q + V lo-half; ng=1 -> full K + V hi-half.
__global__ __launch_bounds__(256) void k_cvtw(const float* __restrict__ wq, const float* __restrict__ wk,
                                              const float* __restrict__ wv, u16* __restrict__ wb){
  int i = blockIdx.x*256 + threadIdx.x;      // 384*2048 total
  int r = i >> 11, k = i & 2047;
  const float* s; int sr;
  if (r < 128)      { s = wq; sr = r; }
  else if (r < 192) { s = wv; sr = r - 128; }
  else if (r < 320) { s = wk; sr = r - 192; }
  else              { s = wv; sr = r - 256; }
  wb[i] = f2bf(s[sr*2048 + k]);
}

// ---------------- fused QKV projection GEMM + RoPE / V^T epilogue ----------------
// grid 256 = 128 M-tiles x 2 N-groups. 512 threads = 8 waves (2M x 4N), wave 64x48.
// BM=128, BN=192, BK=64. LDS 80KB: A bf16 dbuf 2x16KB @0, W bf16 dbuf 2x24KB @32768.
// 2-phase pipeline: stage(t+1) issued BEFORE compute(t); one vmcnt(0)+barrier per step.
// A reg-staged (fp32 global -> cvt once -> swizzled ds_write); W via preswizzled gload_lds.
// XCD-bijective bid map: both N-groups of an M-tile land on the same XCD (x fetched once).
__global__ __launch_bounds__(512,2) void k_gemm(
    const float* __restrict__ x, const u16* __restrict__ wb, const float2* __restrict__ tab,
    u16* __restrict__ qb, u16* __restrict__ kb, u16* __restrict__ vt)
{
  __shared__ char lds[81920];
  const int tid = threadIdx.x;
  const int bid = blockIdx.x;
  const int xcd = bid & 7, li = bid >> 3;
  const int mg = (li >> 1)*8 + xcd;          // 0..127
  const int ng = li & 1;                     // 0..1
  const size_t M0 = (size_t)mg * 128;
  const int w = tid >> 6, lane = tid & 63, lr = lane & 15, lg = lane >> 4;
  const int wm = w >> 2, wn = w & 3;

  // A staging: thread owns (row, 16-k chunk) of the 128x64 tile
  const int arow = tid >> 2, akq = (tid & 3)*16;
  const float* axp = x + (M0 + arow)*DMODEL + akq;
  const int asw  = (arow & 7) << 4;
  const int awb0 = arow*128 + ((2*akq) ^ asw);
  const int awb1 = arow*128 + ((2*akq + 16) ^ asw);

  // W staging: 3 gload16/thread, preswizzled source rows ng*192..+192
  int woff[3], wdst[3];
  #pragma unroll
  for (int i=0;i<3;i++){
    int L = i*8192 + tid*16;
    int row = L >> 7, cb = L & 127;
    int scb = cb ^ ((row & 7) << 4);
    woff[i] = (ng*192 + row)*DMODEL + (scb >> 1);
    wdst[i] = 32768 + L;
  }
  const int slots[3] = {wn, wn+4, 8+wn};     // RoPE lo, RoPE hi, V

  f32x4 acc[4][3];
  #pragma unroll
  for (int i=0;i<4;i++)
    #pragma unroll
    for (int j=0;j<3;j++) acc[i][j] = f32x4{0.f,0.f,0.f,0.f};

  float4v a0, a1, a2, a3;

  // ---- prologue: A(0) loads + W(0) DMA (buf0); cvt+write A(0); drain; barrier ----
  a0 = *(const float4v*)(axp);     a1 = *(const float4v*)(axp + 4);
  a2 = *(const float4v*)(axp + 8); a3 = *(const float4v*)(axp + 12);
  #pragma unroll
  for (int i=0;i<3;i++) gload16(wb + woff[i], lds + wdst[i]);
  {
    short8 o;
    o[0]=(short)f2bf(a0[0]); o[1]=(short)f2bf(a0[1]); o[2]=(short)f2bf(a0[2]); o[3]=(short)f2bf(a0[3]);
    o[4]=(short)f2bf(a1[0]); o[5]=(short)f2bf(a1[1]); o[6]=(short)f2bf(a1[2]); o[7]=(short)f2bf(a1[3]);
    *(short8*)(lds + awb0) = o;
    o[0]=(short)f2bf(a2[0]); o[1]=(short)f2bf(a2[1]); o[2]=(short)f2bf(a2[2]); o[3]=(short)f2bf(a2[3]);
    o[4]=(short)f2bf(a3[0]); o[5]=(short)f2bf(a3[1]); o[6]=(short)f2bf(a3[2]); o[7]=(short)f2bf(a3[3]);
    *(short8*)(lds + awb1) = o;
  }
  __builtin_amdgcn_sched_barrier(0);
  asm volatile("s_waitcnt vmcnt(0) lgkmcnt(0)" ::: "memory");
  __builtin_amdgcn_sched_barrier(0);
  __builtin_amdgcn_s_barrier();
  __builtin_amdgcn_sched_barrier(0);

  for (int t=0; t<32; t++){
    const int p = t & 1;
    // [1] issue stage(t+1): A-loads to regs, W DMA into buf p^1 (read last at t-1, free)
    if (t < 31){
      const float* ap = axp + (t+1)*64;
      a0 = *(const float4v*)(ap);     a1 = *(const float4v*)(ap + 4);
      a2 = *(const float4v*)(ap + 8); a3 = *(const float4v*)(ap + 12);
      const int k0 = (t+1)*64;
      #pragma unroll
      for (int i=0;i<3;i++) gload16(wb + woff[i] + k0, lds + wdst[i] + (p^1)*24576);
    }
    __builtin_amdgcn_sched_barrier(0);
    // [2] compute tile t from Abuf[p], Wbuf[p]
    {
      const char* lA = lds + p*16384;
      const char* lW = lds + p*24576;      // + 32768 folded into read below
      short8 af[2][4];
      #pragma unroll
      for (int ks=0;ks<2;ks++)
        #pragma unroll
        for (int rf=0;rf<4;rf++){
          int r = wm*64 + rf*16 + lr;
          af[ks][rf] = *(const short8*)(lA + r*128 + ((ks*64 + lg*16) ^ ((r&7)<<4)));
        }
      #pragma unroll
      for (int s=0;s<3;s++){
        int lrow = slots[s]*16 + lr;
        #pragma unroll
        for (int ks=0;ks<2;ks++){
          short8 wf = *(const short8*)(lW + 32768 + lrow*128 + ((ks*64 + lg*16) ^ ((lrow&7)<<4)));
          #pragma unroll
          for (int rf=0;rf<4;rf++)
            acc[rf][s] = __builtin_amdgcn_mfma_f32_16x16x32_bf16(af[ks][rf], wf, acc[rf][s], 0,0,0);
        }
      }
    }
    __builtin_amdgcn_sched_barrier(0);
    // [3] write-late: cvt A(t+1) (compiler waits the 4 oldest loads) into Abuf[p^1]
    if (t < 31){
      short8 o;
      o[0]=(short)f2bf(a0[0]); o[1]=(short)f2bf(a0[1]); o[2]=(short)f2bf(a0[2]); o[3]=(short)f2bf(a0[3]);
      o[4]=(short)f2bf(a1[0]); o[5]=(short)f2bf(a1[1]); o[6]=(short)f2bf(a1[2]); o[7]=(short)f2bf(a1[3]);
      *(short8*)(lds + (p^1)*16384 + awb0) = o;
      o[0]=(short)f2bf(a2[0]); o[1]=(short)f2bf(a2[1]); o[2]=(short)f2bf(a2[2]); o[3]=(short)f2bf(a2[3]);
      o[4]=(short)f2bf(a3[0]); o[5]=(short)f2bf(a3[1]); o[6]=(short)f2bf(a3[2]); o[7]=(short)f2bf(a3[3]);
      *(short8*)(lds + (p^1)*16384 + awb1) = o;
    }
    __builtin_amdgcn_sched_barrier(0);
    // [4] W(t+1) DMA + A ds_writes complete; everyone past Wbuf[p] reads
    asm volatile("s_waitcnt vmcnt(0) lgkmcnt(0)" ::: "memory");
    __builtin_amdgcn_sched_barrier(0);
    __builtin_amdgcn_s_barrier();
    __builtin_amdgcn_sched_barrier(0);
  }

  // epilogue: RoPE pair (slots 0,1) -> qb/kb; slot 2 -> V^T
  u16* dst = ng ? kb : qb;
  #pragma unroll
  for (int rf=0; rf<4; rf++)
    #pragma unroll
    for (int reg=0; reg<4; reg++){
      size_t grow = M0 + wm*64 + rf*16 + lg*4 + reg;
      int spos = (int)(grow & (SEQ-1));
      size_t b = grow >> 12;
      int j = wn*16 + lr;
      float2 cs = tab[spos*64 + j];
      float lo = acc[rf][0][reg];
      float hi = acc[rf][1][reg];
      dst[grow*HD + j]      = f2bf(lo*cs.x - hi*cs.y);
      dst[grow*HD + j + 64] = f2bf(hi*cs.x + lo*cs.y);
      int vcol = wn*16 + lr + ng*64;
      vt[(b*HD + vcol)*SEQ + spos] = f2bf(acc[rf][2][reg]);
    }
}

// ---------------- causal flash attention, 4-way KV split (flash-decoding) ----------------
// grid 1024: (batch, 64-row q-tile, kv-split). 4 waves x 16 q-rows share staged lK/lV.
// LDS 40KB -> 4 blocks/CU -> 16 waves/CU. qt descending (heavy first);
// bid&7 -> XCD pairs per batch so each XCD's L2 holds one batch's K+V (2MB).
__global__ __launch_bounds__(256) void k_attn(
    const u16* __restrict__ qbuf, const u16* __restrict__ kb, const u16* __restrict__ vt,
    float* __restrict__ Opart, float2* __restrict__ ml)
{
  __shared__ u16 lK[64*128];    // byte = kv*256 + (cb ^ ((kv&7)<<4))
  __shared__ u16 lV[128*64];    // byte = d*128  + (cb ^ ((d&7)<<4))
  __shared__ u16 lP[4][16*64];  // per-wave, byte = r*128 + (cb ^ ((r&7)<<4))
  const int tid = threadIdx.x;
  const int bid = blockIdx.x;
  const int x = bid & 7, idx = bid >> 3;
  const int b = x >> 1, half = x & 1;
  const int qt = 63 - (idx >> 1);              // heavy tiles first
  const int sp = (idx & 1) + 2*half;           // kv-split 0..3
  const int qbn = b*64 + qt;                   // 0..255
  const int w = tid >> 6, lane = tid & 63, lr = lane & 15, lg = lane >> 4;

  // balanced contiguous partition of tiles [0, qt] into 4 chunks
  const int n = qt + 1, cbase = n >> 2, crem = n & 3;
  const int cnt = cbase + (sp < crem ? 1 : 0);
  const int klo = sp*cbase + (sp < crem ? sp : crem);
  const int khi = klo + cnt;
  const size_t prow0 = ((size_t)qbn*4 + sp)*64;

  if (cnt == 0){                               // empty split: mark and exit (block-uniform)
    if (lr == 0){
      #pragma unroll
      for (int reg=0; reg<4; reg++)
        ml[prow0 + w*16 + lg*4 + reg] = make_float2(-1e30f, 0.f);
    }
    return;
  }

  const size_t qrow = (size_t)b*SEQ + qt*64 + w*16 + lr;
  short8 aq[4];
  #pragma unroll
  for (int ks=0; ks<4; ks++)
    aq[ks] = *(const short8*)(qbuf + qrow*HD + ks*32 + lg*8);

  f32x4 accO[8];
  #pragma unroll
  for (int i=0;i<8;i++) accO[i] = f32x4{0.f,0.f,0.f,0.f};
  float m2[4]   = {-1e30f,-1e30f,-1e30f,-1e30f};
  float lsum[4] = {0.f,0.f,0.f,0.f};

  const int Lb = tid*16;
  const float cfac = SCALE * LOG2E;

  for (int kt = klo; kt < khi; kt++){
    #pragma unroll
    for (int i=0;i<4;i++){
      int L = i*4096 + Lb;
      { int row = L >> 8, cb = L & 255;
        int scb = cb ^ ((row & 7) << 4);
        gload16(kb + ((size_t)b*SEQ + kt*64 + row)*HD + (scb>>1), ((char*)lK) + L); }
      { int row = L >> 7, cb = L & 127;
        int scb = cb ^ ((row & 7) << 4);
        gload16(vt + ((size_t)b*HD + row)*SEQ + kt*64 + (scb>>1), ((char*)lV) + L); }
    }
    __syncthreads();

    // S = Q K^T  (16 q-rows x 64 kv) in log2-domain units
    f32x4 sc[4];
    #pragma unroll
    for (int nf=0; nf<4; nf++){
      sc[nf] = f32x4{0.f,0.f,0.f,0.f};
      #pragma unroll
      for (int ks=0; ks<4; ks++){
        int r = nf*16 + lr;
        int byte = r*256 + ((ks*64 + lg*16) ^ ((r&7)<<4));
        short8 bk = *(const short8*)((const char*)lK + byte);
        sc[nf] = __builtin_amdgcn_mfma_f32_16x16x32_bf16(aq[ks], bk, sc[nf], 0,0,0);
      }
      sc[nf] *= cfac;
    }
    if (kt == qt){                            // diagonal tile: causal mask
      #pragma unroll
      for (int nf=0; nf<4; nf++)
        #pragma unroll
        for (int reg=0; reg<4; reg++){
          int col = nf*16 + lr;
          int row = w*16 + lg*4 + reg;
          if (col > row) sc[nf][reg] = -1e30f;
        }
    }
    float al[4];
    #pragma unroll
    for (int reg=0; reg<4; reg++){
      float v = fmaxf(fmaxf(sc[0][reg], sc[1][reg]), fmaxf(sc[2][reg], sc[3][reg]));
      v = fmaxf(v, __shfl_xor(v, 1));
      v = fmaxf(v, __shfl_xor(v, 2));
      v = fmaxf(v, __shfl_xor(v, 4));
      v = fmaxf(v, __shfl_xor(v, 8));
      float mnew = fmaxf(m2[reg], v);
      al[reg] = exp2f(m2[reg] - mnew);
      m2[reg] = mnew;
    }
    float prs[4] = {0.f,0.f,0.f,0.f};
    #pragma unroll
    for (int nf=0; nf<4; nf++)
      #pragma unroll
      for (int reg=0; reg<4; reg++){
        float p = exp2f(sc[nf][reg] - m2[reg]);
        prs[reg] += p;
        int r = lg*4 + reg;
        int byte = r*128 + ((nf*32 + lr*2) ^ ((r&7)<<4));
        *(u16*)(((char*)lP[w]) + byte) = f2bf(p);
      }
    f32x4 alv = f32x4{al[0], al[1], al[2], al[3]};
    #pragma unroll
    for (int reg=0; reg<4; reg++){
      float v = prs[reg];
      v += __shfl_xor(v, 1);
      v += __shfl_xor(v, 2);
      v += __shfl_xor(v, 4);
      v += __shfl_xor(v, 8);
      lsum[reg] = lsum[reg]*al[reg] + v;
    }
    #pragma unroll
    for (int cf=0; cf<8; cf++) accO[cf] *= alv;

    short8 pa[2];
    #pragma unroll
    for (int ks=0; ks<2; ks++){
      int byte = lr*128 + ((ks*64 + lg*16) ^ ((lr&7)<<4));
      pa[ks] = *(const short8*)(((const char*)lP[w]) + byte);
    }
    #pragma unroll
    for (int cf=0; cf<8; cf++){
      #pragma unroll
      for (int ks=0; ks<2; ks++){
        int d = cf*16 + lr;
        int byte = d*128 + ((ks*64 + lg*16) ^ ((d&7)<<4));
        short8 bv = *(const short8*)(((const char*)lV) + byte);
        accO[cf] = __builtin_amdgcn_mfma_f32_16x16x32_bf16(pa[ks], bv, accO[cf], 0,0,0);
      }
    }
    __syncthreads();
  }

  // partial epilogue: raw accO + (m, l) per row
  #pragma unroll
  for (int reg=0; reg<4; reg++){
    size_t pr = prow0 + w*16 + lg*4 + reg;
    #pragma unroll
    for (int cf=0; cf<8; cf++)
      Opart[pr*HD + cf*16 + lr] = accO[cf][reg];
  }
  if (lr == 0){
    #pragma unroll
    for (int reg=0; reg<4; reg++)
      ml[prow0 + w*16 + lg*4 + reg] = make_float2(m2[reg], lsum[reg]);
  }
}

// ---------------- combine partials: out = sum_s O_s * 2^(m_s-M) / L ----------------
__global__ __launch_bounds__(256) void k_comb(
    const float* __restrict__ Opart, const float2* __restrict__ ml, float* __restrict__ out)
{
  const int t = threadIdx.x;
  const int r = blockIdx.x*8 + (t >> 5);       // global row 0..16383
  const int c = (t & 31)*4;
  const int qbn = r >> 6, rr = r & 63;
  float m[4], l[4], M = -1e30f;
  #pragma unroll
  for (int s=0; s<4; s++){
    float2 v = ml[((size_t)qbn*4 + s)*64 + rr];
    m[s] = v.x; l[s] = v.y;
    M = fmaxf(M, m[s]);
  }
  float L = 0.f;
  #pragma unroll
  for (int s=0; s<4; s++){ m[s] = exp2f(m[s] - M); L += l[s]*m[s]; }
  const float inv = 1.0f / L;
  f32x4 acc = f32x4{0.f,0.f,0.f,0.f};
  #pragma unroll
  for (int s=0; s<4; s++){
    f32x4 o = *(const f32x4*)(Opart + (((size_t)qbn*4 + s)*64 + rr)*(size_t)HD + c);
    float sc = m[s]*inv;
    acc += o * sc;
  }
  *(f32x4*)(out + (size_t)r*HD + c) = acc;
}

extern "C" void kernel_launch(void* const* d_in, const int* in_sizes, int n_in,
                              void* d_out, int out_size, void* d_ws, size_t ws_size,
                              hipStream_t stream){
  const float* x  = (const float*)d_in[0];
  const float* wq = (const float*)d_in[1];
  const float* wk = (const float*)d_in[2];
  const float* wv = (const float*)d_in[3];
  float* out = (float*)d_out;
  char* ws = (char*)d_ws;

  size_t off = 0;
  u16* wb = (u16*)(ws + off); off += (size_t)3*HD*DMODEL*2;     // 1.5 MB
  float2* tab = (float2*)(ws + off); off += (size_t)SEQ*64*8;   // 2 MB
  u16* qb = (u16*)(ws + off); off += (size_t)BS*HD*2;           // 4 MB
  u16* kb = (u16*)(ws + off); off += (size_t)BS*HD*2;           // 4 MB
  u16* vt = (u16*)(ws + off); off += (size_t)BS*HD*2;           // 4 MB
  float* Opart = (float*)(ws + off); off += (size_t)1024*64*HD*4; // 33.5 MB
  float2* ml   = (float2*)(ws + off); off += (size_t)1024*64*8;   // 0.5 MB
  if (ws_size < off) return;  // insufficient workspace -> fail visibly

  hipLaunchKernelGGL(k_tab,  dim3(1024),  dim3(256), 0, stream, tab);
  hipLaunchKernelGGL(k_cvtw, dim3(3072),  dim3(256), 0, stream, wq, wk, wv, wb);
  hipLaunchKernelGGL(k_gemm, dim3(256),   dim3(512), 0, stream, x, wb, tab, qb, kb, vt);
  hipLaunchKernelGGL(k_attn, dim3(1024),  dim3(256), 0, stream, qb, kb, vt, Opart, ml);
  hipLaunchKernelGGL(k_comb, dim3(2048),  dim3(256), 0, stream, Opart, ml, out);
}